// Round 3
// baseline (1342.814 us; speedup 1.0000x reference)
//
#include <hip/hip_runtime.h>
#include <math.h>

#define MULT 32
#define NSPEC 10
#define NGRAPH 16
#define NBANK 64          /* stat replication banks (tp_kernel) */
#define NCBANK 16         /* cnt replication banks (count_kernel) */
#define NCHUNK 32         /* weight stream: 32 chunks x 8KB = 256KB per b */
#define INV_SC 0.05590169943749474f   /* 1/sqrt(32*10) */
#define INV32S 0.17677669529663687f   /* 1/sqrt(32) */

typedef unsigned short u16;
typedef __bf16 v8bf __attribute__((ext_vector_type(8)));
typedef float v4f __attribute__((ext_vector_type(4)));
typedef unsigned int v4u_t __attribute__((ext_vector_type(4)));

__device__ __forceinline__ u16 f2bf(float f) {
    unsigned int u = __builtin_bit_cast(unsigned int, f);
    unsigned int r = u + 0x7fffu + ((u >> 16) & 1u);
    return (u16)(r >> 16);
}

__device__ __forceinline__ v8bf frag16(const u16* p) {
    return __builtin_bit_cast(v8bf, *(const v4u_t*)p);
}

#define MFMA(a, b, c) __builtin_amdgcn_mfma_f32_16x16x32_bf16(a, b, c, 0, 0, 0)

#define GLL(g, l) __builtin_amdgcn_global_load_lds( \
    (const __attribute__((address_space(1))) unsigned int*)(g), \
    (__attribute__((address_space(3))) unsigned int*)(l), 16, 0, 0)

// ---------------------------------------------------------------------------
// small utility kernels
// ---------------------------------------------------------------------------
__global__ void zero_kernel(float* __restrict__ p, int n) {
    int i = blockIdx.x * 256 + threadIdx.x;
    if (i < n) p[i] = 0.0f;
}

__global__ void count_kernel(const int* __restrict__ batch, float* __restrict__ cntb, int N) {
    __shared__ int bins[NGRAPH];
    int t = threadIdx.x;
    if (t < NGRAPH) bins[t] = 0;
    __syncthreads();
    int i = blockIdx.x * 256 + t;
    if (i < N) atomicAdd(&bins[batch[i]], 1);
    __syncthreads();
    int bank = blockIdx.x & (NCBANK - 1);
    if (t < NGRAPH && bins[t] > 0) atomicAdd(&cntb[bank * NGRAPH + t], (float)bins[t]);
}

// ---------------------------------------------------------------------------
// effective-weight precompute (fp32):
//  Weff[path,b][a,bb,z], path: 0=000, 1=110, 2=011, 3=101
// ---------------------------------------------------------------------------
__global__ void stageA_kernel(const float* __restrict__ w000, const float* __restrict__ w110,
                              const float* __restrict__ w011, const float* __restrict__ w101,
                              const float* __restrict__ lp0, const float* __restrict__ lp1,
                              float* __restrict__ tmp1) {
    int gid = blockIdx.x * 256 + threadIdx.x;
    int tslot = gid >> 15;
    int e = gid & 32767;
    int z = e & 31;
    int uv = e >> 5;
    int b = tslot >> 2, path = tslot & 3;
    const float* W = (path == 0 ? w000 : path == 1 ? w110 : path == 2 ? w011 : w101) + b * 32768;
    const float* L = ((path == 0 || path == 1) ? lp0 : lp1) + b * 1024;
    float scale = (path == 1) ? (1.0f / (8192.0f * 1.7320508075688772f)) : (1.0f / 8192.0f);
    const float* wr = W + uv * 32;
    float acc = 0.0f;
    for (int w = 0; w < 32; ++w) acc += wr[w] * L[w * 32 + z];
    tmp1[gid] = acc * scale;
}

__global__ void stageB_kernel(const float* __restrict__ ul0, const float* __restrict__ ul1,
                              const float* __restrict__ tmp1, float* __restrict__ tmp2) {
    int gid = blockIdx.x * 256 + threadIdx.x;
    int tslot = gid >> 15;
    int e = gid & 32767;
    int z = e & 31;
    int bb = (e >> 5) & 31;
    int u = e >> 10;
    int b = tslot >> 2, path = tslot & 3;
    const float* U = ((path == 0 || path == 3) ? ul0 : ul1) + b * 1024;
    const float* in = tmp1 + (size_t)tslot * 32768 + u * 1024 + z;
    float acc = 0.0f;
    for (int v = 0; v < 32; ++v) acc += U[bb * 32 + v] * in[v * 32];
    tmp2[gid] = acc;
}

__global__ void stageC_kernel(const float* __restrict__ hl0, const float* __restrict__ hl1,
                              const float* __restrict__ tmp2, float* __restrict__ Weff) {
    int gid = blockIdx.x * 256 + threadIdx.x;
    int tslot = gid >> 15;
    int e = gid & 32767;
    int z = e & 31;
    int bb = (e >> 5) & 31;
    int a = e >> 10;
    int b = tslot >> 2, path = tslot & 3;
    const float* H = ((path == 0 || path == 2) ? hl0 : hl1) + b * 1024;
    const float* in = tmp2 + (size_t)tslot * 32768 + bb * 32 + z;
    float acc = 0.0f;
    for (int u = 0; u < 32; ++u) acc += H[a * 32 + u] * in[u * 1024];
    Weff[gid] = acc;
}

// ---------------------------------------------------------------------------
// pack kernel: fp32 Weff / sc weights -> bf16.
// W region per b (131072 u16 = 32 chunks of 4096, stream order 000|011|101|110):
//   each 64KB region = 64 blocks of 512 u16; block g: hi = g>>1, zh = g&1.
//   Intra-block layout is LANE-LINEAR for conflict-free ds_read_b128:
//   new[g*512 + lane*8 + j] where lane=(quad*16+c16): k=quad*8+j, z=zh*16+c16.
// SC regions unchanged (read from global):
//  [131072,141312):  WSC0P [s][col=z][k=a]  (x INV_SC)
//  [141312,151552):  WSC1P [s][col=z][k=a]  (x INV_SC)
// ---------------------------------------------------------------------------
__global__ void pack_kernel(const float* __restrict__ Weff,
                            const float* __restrict__ sc_w0, const float* __restrict__ sc_w1,
                            u16* __restrict__ packs, int total) {
    int gid = blockIdx.x * 256 + threadIdx.x;
    if (gid >= total) return;
    int b = gid / 151552;
    int e = gid - b * 151552;
    float v;
    if (e < 131072) {
        int which = e >> 15;          // 0:000 1:011 2:101 3:110 (stream order)
        int e2 = e & 32767;
        int g = e2 >> 9;
        int off = e2 & 511;
        int lane = off >> 3, j = off & 7;
        int c16v = lane & 15, quadv = lane >> 4;
        int k = quadv * 8 + j;
        int z = (g & 1) * 16 + c16v;
        int hi = g >> 1;
        int path = (which == 0) ? 0 : (which == 1) ? 2 : (which == 2) ? 3 : 1;
        int a  = (which < 2) ? k  : hi;
        int bb = (which < 2) ? hi : k;
        v = Weff[(size_t)((b * 4 + path) * 32 + a) * 1024 + bb * 32 + z];
    } else {
        int e2 = e - 131072;
        int which = e2 / 10240;
        int e3 = e2 - which * 10240;
        int s = e3 >> 10, z = (e3 >> 5) & 31, a = e3 & 31;
        const float* S = which ? sc_w1 : sc_w0;
        v = S[(size_t)b * 10240 + a * 320 + s * 32 + z] * INV_SC;
    }
    packs[gid] = f2bf(v);
}

// ---------------------------------------------------------------------------
// MFMA TP + self-connection + stats kernel, v2.
// One WG = 64 nodes (4 waves x 16-node tile; wave owns its full output).
// Weight stream (256KB/b) consumed once per WG through a double-buffered
// 8KB-chunk LDS pipeline (global_load_lds w16, counted vmcnt, raw s_barrier).
// A-fragments in registers; stage-2 multipliers in LDS [row][64].
// ---------------------------------------------------------------------------
__global__ __launch_bounds__(256, 2)
void tp_kernel(const float* __restrict__ hidden_b, const float* __restrict__ up,
               const u16* __restrict__ pk,
               const float* __restrict__ lp_b0,
               const int* __restrict__ species, const int* __restrict__ batch,
               float* __restrict__ S1b, float* __restrict__ S2b, float* __restrict__ V2b,
               float* __restrict__ zout, int N) {
    __shared__ __align__(16) float ybuf[14336];   // yS[2048] yV[6144] yH[6144]
    __shared__ __align__(16) u16 wbuf[2][4096];   // 2 x 8KB weight chunks
    __shared__ float gs1[NGRAPH], gs2[NGRAPH], gv2[NGRAPH];

    float* yS = ybuf;            // [32 bb][64 nl]  (su)
    float* yV = ybuf + 2048;     // [3][32][64]     (vu)
    float* yH = ybuf + 8192;     // [3][32][64]     (vh)

    const int t = threadIdx.x;
    const int wv = t >> 6, lane = t & 63, quad = lane >> 4, c16 = lane & 15;
    const int n0 = blockIdx.x * 64;
    const int nvalid = min(64, N - n0);
    const u16* wsrc = pk;                       // W stream base (131072 u16)
    const u16* pkSC0 = pk + 131072;
    const u16* pkSC1 = pk + 141312;

#define STAGE(ch, bf) do { \
        const u16* gsrc_ = wsrc + (ch) * 4096 + wv * 1024 + lane * 8; \
        GLL(gsrc_, &wbuf[bf][wv * 1024]); \
        GLL(gsrc_ + 512, &wbuf[bf][wv * 1024 + 512]); \
    } while (0)

    // prologue: prefetch chunks 0,1
    STAGE(0, 0);
    STAGE(1, 1);

    if (t < NGRAPH) { gs1[t] = 0.f; gs2[t] = 0.f; gv2[t] = 0.f; }

    // ---- A-fragment register loads (lane c16 = node row, quad = k-group) ----
    const int myloc = wv * 16 + c16;
    const bool av_ok = myloc < nvalid;
    const int myn = n0 + (av_ok ? myloc : 0);
    int sp = -1;
    v8bf a_sh, a_su, a_vh[3], a_vu[3];
    const v8bf zf = __builtin_bit_cast(v8bf, (v4u_t){0u, 0u, 0u, 0u});
    {
        const float* hrow = hidden_b + (size_t)myn * 128;
        const float* urow = up + (size_t)myn * 128;
        v4f h0 = *(const v4f*)(hrow + quad * 8), h1 = *(const v4f*)(hrow + quad * 8 + 4);
        v4f u0 = *(const v4f*)(urow + quad * 8), u1 = *(const v4f*)(urow + quad * 8 + 4);
        v4u_t ws, wu;
#pragma unroll
        for (int k = 0; k < 2; ++k) {
            ws[k]     = f2bf(h0[2*k]) | ((unsigned)f2bf(h0[2*k+1]) << 16);
            ws[k + 2] = f2bf(h1[2*k]) | ((unsigned)f2bf(h1[2*k+1]) << 16);
            wu[k]     = f2bf(u0[2*k]) | ((unsigned)f2bf(u0[2*k+1]) << 16);
            wu[k + 2] = f2bf(u1[2*k]) | ((unsigned)f2bf(u1[2*k+1]) << 16);
        }
        a_sh = __builtin_bit_cast(v8bf, ws);
        a_su = __builtin_bit_cast(v8bf, wu);
        float hv24[24], uv24[24];
#pragma unroll
        for (int q2 = 0; q2 < 6; ++q2) {
            v4f hv = *(const v4f*)(hrow + 32 + quad * 24 + q2 * 4);
            v4f uv = *(const v4f*)(urow + 32 + quad * 24 + q2 * 4);
#pragma unroll
            for (int jj = 0; jj < 4; ++jj) { hv24[q2*4+jj] = hv[jj]; uv24[q2*4+jj] = uv[jj]; }
        }
#pragma unroll
        for (int c = 0; c < 3; ++c) {
            v4u_t wh, wv2;
#pragma unroll
            for (int k = 0; k < 4; ++k) {
                wh[k]  = f2bf(hv24[(2*k)*3 + c]) | ((unsigned)f2bf(hv24[(2*k+1)*3 + c]) << 16);
                wv2[k] = f2bf(uv24[(2*k)*3 + c]) | ((unsigned)f2bf(uv24[(2*k+1)*3 + c]) << 16);
            }
            a_vh[c] = __builtin_bit_cast(v8bf, wh);
            a_vu[c] = __builtin_bit_cast(v8bf, wv2);
        }
        if (!av_ok) {
            a_sh = zf; a_su = zf;
#pragma unroll
            for (int c = 0; c < 3; ++c) { a_vh[c] = zf; a_vu[c] = zf; }
        } else {
            sp = species[myn];
        }
    }

    // ---- stage-2 multiplier staging: y arrays [row][64], conflict-free ----
    {
        const int nl = t & 63, cc = t >> 6;
        const bool nok = nl < nvalid;
        const float* hr = hidden_b + (size_t)(n0 + (nok ? nl : 0)) * 128 + cc * 32;
        const float* ur = up + (size_t)(n0 + (nok ? nl : 0)) * 128 + cc * 32;
        const v4f z4s = {0.f, 0.f, 0.f, 0.f};
        if (cc == 0) {
#pragma unroll
            for (int j4 = 0; j4 < 8; ++j4) {
                v4f uv = nok ? *(const v4f*)(ur + j4 * 4) : z4s;
#pragma unroll
                for (int jj = 0; jj < 4; ++jj) yS[(j4 * 4 + jj) * 64 + nl] = uv[jj];
            }
        } else {
#pragma unroll
            for (int j4 = 0; j4 < 8; ++j4) {
                v4f hv = nok ? *(const v4f*)(hr + j4 * 4) : z4s;
                v4f uv = nok ? *(const v4f*)(ur + j4 * 4) : z4s;
#pragma unroll
                for (int jj = 0; jj < 4; ++jj) {
                    int idx = (cc - 1) * 32 + j4 * 4 + jj;   // 0..95
                    int a = (idx * 171) >> 9;                // idx/3
                    int c = idx - a * 3;
                    yV[(c * 32 + a) * 64 + nl] = uv[jj];
                    yH[(c * 32 + a) * 64 + nl] = hv[jj];
                }
            }
        }
    }
    __syncthreads();

    // ---- main weight-stream loop ----
    const v4f z4 = {0.f, 0.f, 0.f, 0.f};
    const int yb = wv * 16 + quad * 4;
    v4f o0[2];
    v4f o1[3][2];
    o0[0] = z4; o0[1] = z4;
#pragma unroll
    for (int c = 0; c < 3; ++c) { o1[c][0] = z4; o1[c][1] = z4; }

#define RD_WF(bf, pr) \
    v8bf wf0 = frag16(&wbuf[bf][(pr) * 1024 + lane * 8]); \
    v8bf wf1 = frag16(&wbuf[bf][(pr) * 1024 + 512 + lane * 8]);

#define BODY_000 { RD_WF(buf, pr) \
    v4f y = *(const v4f*)(yS + hi * 64 + yb); \
    v4f C0 = MFMA(a_sh, wf0, z4); v4f C1 = MFMA(a_sh, wf1, z4); \
    _Pragma("unroll") for (int r = 0; r < 4; ++r) { o0[0][r] += C0[r] * y[r]; o0[1][r] += C1[r] * y[r]; } }

#define BODY_011 { RD_WF(buf, pr) \
    v4f C0 = MFMA(a_sh, wf0, z4); v4f C1 = MFMA(a_sh, wf1, z4); \
    _Pragma("unroll") for (int c = 0; c < 3; ++c) { \
        v4f y = *(const v4f*)(yV + (c * 32 + hi) * 64 + yb); \
        _Pragma("unroll") for (int r = 0; r < 4; ++r) { o1[c][0][r] += C0[r] * y[r]; o1[c][1][r] += C1[r] * y[r]; } } }

#define BODY_101 { RD_WF(buf, pr) \
    v4f C0 = MFMA(a_su, wf0, z4); v4f C1 = MFMA(a_su, wf1, z4); \
    _Pragma("unroll") for (int c = 0; c < 3; ++c) { \
        v4f y = *(const v4f*)(yH + (c * 32 + hi) * 64 + yb); \
        _Pragma("unroll") for (int r = 0; r < 4; ++r) { o1[c][0][r] += C0[r] * y[r]; o1[c][1][r] += C1[r] * y[r]; } } }

#define BODY_110 { RD_WF(buf, pr) \
    _Pragma("unroll") for (int c = 0; c < 3; ++c) { \
        v4f y = *(const v4f*)(yH + (c * 32 + hi) * 64 + yb); \
        v4f C0 = MFMA(a_vu[c], wf0, z4); v4f C1 = MFMA(a_vu[c], wf1, z4); \
        _Pragma("unroll") for (int r = 0; r < 4; ++r) { o0[0][r] += C0[r] * y[r]; o0[1][r] += C1[r] * y[r]; } } }

#define SECTION(SEC, WAITASM, BODY) \
    for (int c8 = 0; c8 < 8; ++c8) { \
        const int ch = (SEC) * 8 + c8; \
        const int buf = ch & 1; \
        asm volatile(WAITASM ::: "memory"); \
        __builtin_amdgcn_s_barrier(); \
        _Pragma("unroll") \
        for (int pr = 0; pr < 4; ++pr) { \
            const int hi = c8 * 4 + pr; \
            BODY \
        } \
        __builtin_amdgcn_s_barrier(); \
        if (ch + 2 < NCHUNK) STAGE(ch + 2, buf); \
    }

    SECTION(0, "s_waitcnt vmcnt(2)", BODY_000)
    SECTION(1, "s_waitcnt vmcnt(2)", BODY_011)
    SECTION(2, "s_waitcnt vmcnt(2)", BODY_101)
    SECTION(3, "s_waitcnt vmcnt(0)", BODY_110)

    // ---- self connection: per-wave all species, masked A-frags ----
    {
#pragma unroll 1
        for (int si = 0; si < NSPEC; ++si) {
            if (__any(sp == si)) {
                bool m = (sp == si);
                v8bf ash_m = m ? a_sh : zf;
#pragma unroll
                for (int zh = 0; zh < 2; ++zh) {
                    int boff = (si * 32 + zh * 16 + c16) * 32 + quad * 8;
                    v8bf bf0 = frag16(pkSC0 + boff);
                    v8bf bf1 = frag16(pkSC1 + boff);
                    o0[zh] = MFMA(ash_m, bf0, o0[zh]);
#pragma unroll
                    for (int c = 0; c < 3; ++c) {
                        v8bf am = m ? a_vh[c] : zf;
                        o1[c][zh] = MFMA(am, bf1, o1[c][zh]);
                    }
                }
            }
        }
    }

    // ---- per-wave epilogue through freed y-LDS (no cross-wave barrier) ----
    {
        float bias0 = lp_b0[c16], bias1 = lp_b0[16 + c16];
        float* row_base = ybuf + wv * 2112;       // [16][132]
#pragma unroll
        for (int r = 0; r < 4; ++r) {
            int n = quad * 4 + r;
            float* row = row_base + n * 132;
            row[c16]      = o0[0][r] + bias0;
            row[16 + c16] = o0[1][r] + bias1;
#pragma unroll
            for (int c = 0; c < 3; ++c) {
                row[32 + c16 * 3 + c]        = o1[c][0][r];
                row[32 + (16 + c16) * 3 + c] = o1[c][1][r];
            }
        }
        // wave-internal LDS write->read: compiler inserts lgkmcnt wait
        int rr = lane >> 2, seg = lane & 3;
        const float* rp = row_base + rr * 132 + seg * 32;
        v4f sa[8];
#pragma unroll
        for (int k = 0; k < 8; ++k) sa[k] = *(const v4f*)(rp + k * 4);
        const int gn = n0 + wv * 16 + rr;
        const bool ok = (wv * 16 + rr) < nvalid;
        if (ok) {
            float* op = zout + (size_t)gn * 128 + seg * 32;
#pragma unroll
            for (int k = 0; k < 8; ++k) *(v4f*)(op + k * 4) = sa[k];
        }
        float s1p = 0.f, s2p = 0.f, v2p = 0.f;
        if (seg == 0) {
#pragma unroll
            for (int k = 0; k < 8; ++k)
#pragma unroll
                for (int jj = 0; jj < 4; ++jj) { s1p += sa[k][jj]; s2p += sa[k][jj] * sa[k][jj]; }
        } else {
#pragma unroll
            for (int k = 0; k < 8; ++k)
#pragma unroll
                for (int jj = 0; jj < 4; ++jj) v2p += sa[k][jj] * sa[k][jj];
        }
        s1p += __shfl_xor(s1p, 1, 4); s1p += __shfl_xor(s1p, 2, 4);
        s2p += __shfl_xor(s2p, 1, 4); s2p += __shfl_xor(s2p, 2, 4);
        v2p += __shfl_xor(v2p, 1, 4); v2p += __shfl_xor(v2p, 2, 4);
        if (seg == 0 && ok) {
            int g = batch[gn];
            atomicAdd(&gs1[g], s1p);
            atomicAdd(&gs2[g], s2p);
            atomicAdd(&gv2[g], v2p);
        }
    }
    __syncthreads();
    {
        const int bank = blockIdx.x & (NBANK - 1);
        if (t < NGRAPH) {
            if (gs1[t] != 0.f) atomicAdd(&S1b[bank * NGRAPH + t], gs1[t]);
            if (gs2[t] != 0.f) atomicAdd(&S2b[bank * NGRAPH + t], gs2[t]);
            if (gv2[t] != 0.f) atomicAdd(&V2b[bank * NGRAPH + t], gv2[t]);
        }
    }
#undef STAGE
#undef RD_WF
#undef BODY_000
#undef BODY_011
#undef BODY_101
#undef BODY_110
#undef SECTION
}

// ---------------------------------------------------------------------------
// LayerNorm + skip kernel (in-place on z written by tp_kernel).
// Prologue reduces the replicated stat banks in-WG (L2-resident reads).
// ---------------------------------------------------------------------------
__global__ __launch_bounds__(256)
void norm_kernel(const float* __restrict__ hidden_b, float* __restrict__ out_b,
                 const float* __restrict__ skw0, const float* __restrict__ skb0,
                 const float* __restrict__ skw1,
                 const float* __restrict__ lnw0, const float* __restrict__ lnb0,
                 const float* __restrict__ lnw1,
                 const int* __restrict__ batch,
                 const float* __restrict__ S1b, const float* __restrict__ S2b,
                 const float* __restrict__ V2b, const float* __restrict__ cntb, int N) {
    __shared__ __align__(16) float sh_l[8][32];
    __shared__ __align__(16) float vh_l[8][96];
    __shared__ float stat_s[3][NGRAPH];
    __shared__ float cnt_s[NGRAPH];
    const int t = threadIdx.x, z = t & 31, nl = t >> 5;
    const int n0 = blockIdx.x * 8;
    for (int i = t; i < 8 * 128; i += 256) {
        int n = i >> 7, col = i & 127;
        float v = (n0 + n < N) ? hidden_b[(size_t)(n0 + n) * 128 + col] : 0.f;
        if (col < 32) sh_l[n][col] = v; else vh_l[n][col - 32] = v;
    }
    if (t < 48) {
        int arr = t >> 4, g = t & 15;
        const float* base = (arr == 0) ? S1b : (arr == 1) ? S2b : V2b;
        float s = 0.f;
        for (int k = 0; k < NBANK; ++k) s += base[k * NGRAPH + g];
        stat_s[arr][g] = s;
    } else if (t < 64) {
        int g = t - 48;
        float c = 0.f;
        for (int k = 0; k < NCBANK; ++k) c += cntb[k * NGRAPH + g];
        cnt_s[g] = c;
    }
    __syncthreads();
    const int n = n0 + nl;
    if (n >= N) return;

    float sk0 = 0.f, s1 = 0.f, s2 = 0.f, s3 = 0.f;
    for (int a = 0; a < 32; ++a) {
        float w0 = skw0[a * 32 + z];
        float w1 = skw1[a * 32 + z];
        sk0 += sh_l[nl][a] * w0;
        s1 += vh_l[nl][a * 3 + 0] * w1;
        s2 += vh_l[nl][a * 3 + 1] * w1;
        s3 += vh_l[nl][a * 3 + 2] * w1;
    }
    int g = batch[n];
    float cM = fmaxf(cnt_s[g], 1.0f) * 32.0f;
    float mean = stat_s[0][g] / cM;
    float var = fmaxf(stat_s[1][g] / cM - mean * mean, 0.0f);
    float rs = rsqrtf(var + 1e-5f);
    float rv = rsqrtf(fmaxf(stat_s[2][g] / cM, 0.0f) + 1e-5f);

    size_t base = (size_t)n * 128;
    float z0 = out_b[base + z];
    out_b[base + z] = (z0 - mean) * rs * lnw0[z] + lnb0[z] + sk0 * INV32S + skb0[z];
    float lw = lnw1[z] * rv;
    float x0 = out_b[base + 32 + z * 3 + 0];
    float x1 = out_b[base + 32 + z * 3 + 1];
    float x2 = out_b[base + 32 + z * 3 + 2];
    out_b[base + 32 + z * 3 + 0] = x0 * lw + s1 * INV32S;
    out_b[base + 32 + z * 3 + 1] = x1 * lw + s2 * INV32S;
    out_b[base + 32 + z * 3 + 2] = x2 * lw + s3 * INV32S;
}

// ---------------------------------------------------------------------------
// Workspace layout (total = 2 MiB + 25.6 KiB for B=2):
//   tmp1  [0,       1 MiB)  : stageA out; REUSED as Weff (stageC out)
//   tmp2  [1 MiB,   2 MiB)  : stageB out; REUSED as bf16 packs (pack out)
//   cntb  [2 MiB, +1 KiB)   : cnt banks [NCBANK][16]
//   S1b/S2b/V2b             : stat banks [B][NBANK][16] each
// ---------------------------------------------------------------------------
extern "C" void kernel_launch(void* const* d_in, const int* in_sizes, int n_in,
                              void* d_out, int out_size, void* d_ws, size_t ws_size,
                              hipStream_t stream) {
    const float* hidden = (const float*)d_in[0];
    const float* up0    = (const float*)d_in[1];
    const float* hl_w0  = (const float*)d_in[2];
    const float* hl_w1  = (const float*)d_in[3];
    const float* ul_w0  = (const float*)d_in[4];
    const float* ul_w1  = (const float*)d_in[5];
    const float* w000   = (const float*)d_in[6];
    const float* w110   = (const float*)d_in[7];
    const float* w011   = (const float*)d_in[8];
    const float* w101   = (const float*)d_in[9];
    const float* lp_w0  = (const float*)d_in[10];
    const float* lp_b0  = (const float*)d_in[11];
    const float* lp_w1  = (const float*)d_in[12];
    const float* sc_w0  = (const float*)d_in[13];
    const float* sc_w1  = (const float*)d_in[14];
    const float* ln_w0  = (const float*)d_in[15];
    const float* ln_b0  = (const float*)d_in[16];
    const float* ln_w1  = (const float*)d_in[17];
    const float* sk_w0  = (const float*)d_in[18];
    const float* sk_b0  = (const float*)d_in[19];
    const float* sk_w1  = (const float*)d_in[20];
    const int* species  = (const int*)d_in[21];
    const int* batch    = (const int*)d_in[22];
    float* out = (float*)d_out;

    const int N = in_sizes[21];
    const int B = in_sizes[0] / (N * 128);

    float* ws = (float*)d_ws;
    float* tmp1 = ws;                                  // stageA out -> Weff
    float* tmp2 = tmp1 + (size_t)B * 4 * 32768;        // stageB out -> packs
    float* cntb = tmp2 + (size_t)B * 4 * 32768;        // [NCBANK][16]
    float* S1b = cntb + NCBANK * NGRAPH;               // [B][NBANK][16]
    float* S2b = S1b + (size_t)B * NBANK * NGRAPH;
    float* V2b = S2b + (size_t)B * NBANK * NGRAPH;
    int statn = NCBANK * NGRAPH + 3 * B * NBANK * NGRAPH;

    zero_kernel<<<(statn + 255) / 256, 256, 0, stream>>>(cntb, statn);
    count_kernel<<<(N + 255) / 256, 256, 0, stream>>>(batch, cntb, N);

    int nb = B * 4 * 32768 / 256;
    stageA_kernel<<<nb, 256, 0, stream>>>(w000, w110, w011, w101, lp_w0, lp_w1, tmp1);
    stageB_kernel<<<nb, 256, 0, stream>>>(ul_w0, ul_w1, tmp1, tmp2);
    stageC_kernel<<<nb, 256, 0, stream>>>(hl_w0, hl_w1, tmp2, tmp1);   // Weff -> tmp1

    u16* packs = (u16*)tmp2;                           // tmp2 dead after stageC
    int ptotal = B * 151552;
    pack_kernel<<<(ptotal + 255) / 256, 256, 0, stream>>>(tmp1, sc_w0, sc_w1, packs, ptotal);

    for (int b = 0; b < B; ++b) {
        const float* up = (b == 0) ? up0 : out + (size_t)(b - 1) * N * 128;
        const u16* pb = packs + (size_t)b * 151552;
        tp_kernel<<<(N + 63) / 64, 256, 0, stream>>>(
            hidden + (size_t)b * N * 128, up, pb,
            lp_b0 + b * MULT, species, batch,
            S1b + (size_t)b * NBANK * NGRAPH, S2b + (size_t)b * NBANK * NGRAPH,
            V2b + (size_t)b * NBANK * NGRAPH,
            out + (size_t)b * N * 128, N);
        norm_kernel<<<(N + 7) / 8, 256, 0, stream>>>(
            hidden + (size_t)b * N * 128, out + (size_t)b * N * 128,
            sk_w0 + b * 1024, sk_b0 + b * MULT, sk_w1 + b * 1024,
            ln_w0 + b * MULT, ln_b0 + b * MULT, ln_w1 + b * MULT,
            batch, S1b + (size_t)b * NBANK * NGRAPH, S2b + (size_t)b * NBANK * NGRAPH,
            V2b + (size_t)b * NBANK * NGRAPH, cntb, N);
    }
}